// Round 6
// baseline (708.758 us; speedup 1.0000x reference)
//
#include <hip/hip_runtime.h>

// Performer attention (HyperGTConv): N=50000, C=256, H=8, D=M=64.
// Round 6: structural x-reuse in kv_kernel — ONE block computes ALL heads for
// its slice (wave = 2 heads, full-KV accumulator in registers, bf16 partials).
// x read once device-wide; no reliance on cross-block L2 dedup or XCD mapping.
// S (slices) chosen from ws_size; G=4 fallback variant if ws is tight.

#define NN      50000
#define HDIM    512
#define EPSF    1e-6f
#define SCALE   0.044194173824159224f   // (1/sqrt(64)) * 64^(-1/4)
#define NCH32   1563                    // ceil(50000/32)
#define NCH128  391                     // ceil(50000/128) (out_kernel)
#define LDPA    72                      // out_kernel strip pitch
#define LDPB    40                      // kv transposed strip pitch

typedef __bf16 bf16;
typedef __bf16 bf16x4 __attribute__((ext_vector_type(4)));
typedef __bf16 bf16x8 __attribute__((ext_vector_type(8)));
typedef float  f32x4  __attribute__((ext_vector_type(4)));

#define MFMA(a, b, c) __builtin_amdgcn_mfma_f32_16x16x32_bf16((a), (b), (c), 0, 0, 0)

__device__ __forceinline__ void lds_fence() {
    asm volatile("s_waitcnt lgkmcnt(0)" ::: "memory");
}

// ---------- xconv: x fp32 -> bf16 ----------
__global__ void xconv_kernel(const float* __restrict__ x, bf16* __restrict__ xb)
{
    for (int i8 = blockIdx.x * 256 + threadIdx.x; i8 < NN * 256 / 8;
         i8 += gridDim.x * 256) {
        const float4 a = reinterpret_cast<const float4*>(x)[i8 * 2];
        const float4 b = reinterpret_cast<const float4*>(x)[i8 * 2 + 1];
        bf16x8 r;
        r[0] = (bf16)a.x; r[1] = (bf16)a.y; r[2] = (bf16)a.z; r[3] = (bf16)a.w;
        r[4] = (bf16)b.x; r[5] = (bf16)b.y; r[6] = (bf16)b.z; r[7] = (bf16)b.w;
        reinterpret_cast<bf16x8*>(xb)[i8] = r;
    }
}

// ---------- prep: folded + transposed bf16 weights ----------
__global__ void prep_kernel(const float* __restrict__ Wq, const float* __restrict__ bq,
                            const float* __restrict__ Wk, const float* __restrict__ bk,
                            const float* __restrict__ Wv, const float* __restrict__ Wo,
                            const float* __restrict__ proj,
                            bf16* __restrict__ WqpT, bf16* __restrict__ WkpT,
                            bf16* __restrict__ WvT, bf16* __restrict__ WoT,
                            float* __restrict__ fqb, float* __restrict__ fkb)
{
    const int t = blockIdx.x * 256 + threadIdx.x;
    if (t < 131072) {                       // WqpT/WkpT [h*64+m][c] = sum_d W[c][h,d] proj[m][d]
        const int row = t >> 8, c = t & 255;
        const int hh = row >> 6, m = row & 63;
        const float* pr = proj + m * 64;
        const float* wq = Wq + (size_t)c * HDIM + hh * 64;
        const float* wk = Wk + (size_t)c * HDIM + hh * 64;
        float sq = 0.f, sk = 0.f;
        for (int d = 0; d < 64; ++d) { const float p = pr[d]; sq += wq[d] * p; sk += wk[d] * p; }
        WqpT[(size_t)row * 256 + c] = (bf16)sq;
        WkpT[(size_t)row * 256 + c] = (bf16)sk;
    } else if (t < 262144) {                // WvT[col][c] = Wv[c][col]
        const int i = t - 131072;
        const int col = i >> 8, c = i & 255;
        WvT[i] = (bf16)Wv[(size_t)c * HDIM + col];
    } else if (t < 262144 + 32768) {        // WoT[j][dp] = Wo[dp][j]
        const int i = t - 262144;
        const int j = i >> 9, dp = i & 511;
        WoT[i] = (bf16)Wo[(size_t)dp * 64 + j];
    } else if (t < 262144 + 32768 + 1024) { // fqb/fkb[h*64+m] = sum_d b[h,d] proj[m][d]
        const int i = t - 262144 - 32768;
        const int which = i >> 9, row = i & 511;
        const int hh = row >> 6, m = row & 63;
        const float* pr = proj + m * 64;
        const float* b = (which ? bk : bq) + hh * 64;
        float s = 0.f;
        for (int d = 0; d < 64; ++d) s += b[d] * pr[d];
        (which ? fkb : fqb)[row] = s;
    }
}

// ---------- kernel 1: all-heads-per-block KV partials ----------
// HPW = heads per wave (2 or 1); BSH = log2(blocks per slice) (0 or 1).
// Block covers G = 4*HPW heads; grid = S << BSH. Zero __syncthreads.
template <int HPW, int BSH>
__global__ __launch_bounds__(256, 2)
void kv_kernel(const bf16* __restrict__ xb,
               const bf16* __restrict__ WkpT, const float* __restrict__ fkb,
               const bf16* __restrict__ WvT,  const float* __restrict__ bv,
               bf16* __restrict__ pKV, float* __restrict__ pSum, int S)
{
    __shared__ __align__(16) bf16 pool[4][2][64 * LDPB];   // 40960 B
    const int t  = threadIdx.x;
    const int w  = t >> 6;
    const int l  = t & 63;
    const int lr = l & 15;
    const int lk = l >> 4;

    const int slice = blockIdx.x >> BSH;
    const int hA    = (blockIdx.x & ((1 << BSH) - 1)) * (4 * HPW) + w * HPW;

    bf16* kptbuf = pool[w][0];   // [64 m][LDPB n]
    bf16* vtbuf  = pool[w][1];   // [64 d][LDPB n]

    f32x4 kvacc[HPW][16];
#pragma unroll
    for (int p = 0; p < HPW; ++p)
#pragma unroll
        for (int i = 0; i < 16; ++i) kvacc[p][i] = (f32x4){0.f, 0.f, 0.f, 0.f};
    float ksum_acc[HPW][4];
#pragma unroll
    for (int p = 0; p < HPW; ++p)
#pragma unroll
        for (int q = 0; q < 4; ++q) ksum_acc[p][q] = 0.f;

    float fkbc[HPW][4], bvc[HPW][4];
#pragma unroll
    for (int p = 0; p < HPW; ++p)
#pragma unroll
        for (int q = 0; q < 4; ++q) {
            fkbc[p][q] = fkb[(hA + p) * 64 + q * 16 + lr];
            bvc [p][q] = bv [(hA + p) * 64 + q * 16 + lr];
        }

    for (int chunk = slice; chunk < NCH32; chunk += S) {
        const int nbase = chunk * 32;
        const int r0 = min(nbase + lr,      NN - 1);
        const int r1 = min(nbase + 16 + lr, NN - 1);
        const bf16* xb0 = xb + (size_t)r0 * 256;
        const bf16* xb1 = xb + (size_t)r1 * 256;

#pragma unroll
        for (int p = 0; p < HPW; ++p) {
            const int hh = hA + p;

            // ---- Kfeat = x@Wkp + fkb ; V = x@Wv + bv (shared x A-frags) ----
            f32x4 fK[2][4], aV[2][4];
#pragma unroll
            for (int q = 0; q < 4; ++q) {
                fK[0][q] = (f32x4){fkbc[p][q], fkbc[p][q], fkbc[p][q], fkbc[p][q]};
                fK[1][q] = fK[0][q];
                aV[0][q] = (f32x4){bvc[p][q], bvc[p][q], bvc[p][q], bvc[p][q]};
                aV[1][q] = aV[0][q];
            }
#pragma unroll
            for (int kk = 0; kk < 8; ++kk) {
                const int off = kk * 32 + lk * 8;
                const bf16x8 xa0 = *reinterpret_cast<const bf16x8*>(xb0 + off);
                const bf16x8 xa1 = *reinterpret_cast<const bf16x8*>(xb1 + off);
#pragma unroll
                for (int mt = 0; mt < 4; ++mt) {
                    const bf16x8 wb = *reinterpret_cast<const bf16x8*>(
                        &WkpT[(size_t)(hh * 64 + mt * 16 + lr) * 256 + off]);
                    fK[0][mt] = MFMA(xa0, wb, fK[0][mt]);
                    fK[1][mt] = MFMA(xa1, wb, fK[1][mt]);
                }
#pragma unroll
                for (int dt = 0; dt < 4; ++dt) {
                    const bf16x8 wb = *reinterpret_cast<const bf16x8*>(
                        &WvT[(size_t)(hh * 64 + dt * 16 + lr) * 256 + off]);
                    aV[0][dt] = MFMA(xa0, wb, aV[0][dt]);
                    aV[1][dt] = MFMA(xa1, wb, aV[1][dt]);
                }
            }

            lds_fence();   // previous pass's kpa/vb ds_reads drained
            // ---- exp -> Kp^T [m][n]; V^T [d][n]; zero invalid rows ----
#pragma unroll
            for (int rt = 0; rt < 2; ++rt)
#pragma unroll
                for (int q = 0; q < 4; ++q) {
                    bf16x4 kp4, vv4;
#pragma unroll
                    for (int r = 0; r < 4; ++r) {
                        const int nl = rt * 16 + lk * 4 + r;
                        const bool valid = (nbase + nl) < NN;
                        const float kpv = valid ? (__expf(SCALE * fK[rt][q][r]) + EPSF) : 0.f;
                        ksum_acc[p][q] += kpv;
                        kp4[r] = (bf16)kpv;
                        vv4[r] = valid ? (bf16)aV[rt][q][r] : (bf16)0.f;
                    }
                    *reinterpret_cast<bf16x4*>(
                        &kptbuf[(q * 16 + lr) * LDPB + rt * 16 + lk * 4]) = kp4;
                    *reinterpret_cast<bf16x4*>(
                        &vtbuf [(q * 16 + lr) * LDPB + rt * 16 + lk * 4]) = vv4;
                }
            lds_fence();   // writes visible to whole wave

            // ---- KV += Kp^T @ V (k = 32 rows, single K-step) ----
            bf16x8 kpa[4], vb[4];
#pragma unroll
            for (int mt = 0; mt < 4; ++mt)
                kpa[mt] = *reinterpret_cast<const bf16x8*>(
                    &kptbuf[(mt * 16 + lr) * LDPB + lk * 8]);
#pragma unroll
            for (int dt = 0; dt < 4; ++dt)
                vb[dt] = *reinterpret_cast<const bf16x8*>(
                    &vtbuf[(dt * 16 + lr) * LDPB + lk * 8]);
#pragma unroll
            for (int mt = 0; mt < 4; ++mt)
#pragma unroll
                for (int dt = 0; dt < 4; ++dt)
                    kvacc[p][mt * 4 + dt] = MFMA(kpa[mt], vb[dt], kvacc[p][mt * 4 + dt]);
        }
    }

    // ---- epilogue (per-wave, no barriers): bf16 partial KV + fp32 ksum ----
#pragma unroll
    for (int p = 0; p < HPW; ++p) {
        const int hh = hA + p;
        bf16* dst = pKV + ((size_t)hh * S + slice) * 4096;
#pragma unroll
        for (int mt = 0; mt < 4; ++mt)
#pragma unroll
            for (int dt = 0; dt < 4; ++dt) {
                bf16x4 v4;
#pragma unroll
                for (int r = 0; r < 4; ++r) v4[r] = (bf16)kvacc[p][mt * 4 + dt][r];
                // rows m = mt*16+lk*4+r share no lanes; write 4 rows scalar
#pragma unroll
                for (int r = 0; r < 4; ++r)
                    dst[(mt * 16 + lk * 4 + r) * 64 + dt * 16 + lr] = v4[r];
            }
#pragma unroll
        for (int q = 0; q < 4; ++q) {
            float s = ksum_acc[p][q];
            s += __shfl_xor(s, 16, 64);
            s += __shfl_xor(s, 32, 64);
            if (lk == 0)
                pSum[((size_t)hh * S + slice) * 64 + q * 16 + lr] = s;
        }
    }
}

// ---------- reduce: bf16 partials -> KVT bf16 [h][d][m] + Ksum fp32 ----------
__global__ void reduce_kernel(const bf16* __restrict__ pKV, const float* __restrict__ pSum,
                              bf16* __restrict__ KVT, float* __restrict__ Ksum, int S)
{
    const int idx = blockIdx.x * 256 + threadIdx.x;
    if (idx < 8 * 4096) {
        const int h = idx >> 12, md = idx & 4095;
        const int m = md >> 6, d = md & 63;
        float s = 0.f;
        for (int b = 0; b < S; ++b) s += (float)pKV[((size_t)h * S + b) * 4096 + md];
        KVT[h * 4096 + d * 64 + m] = (bf16)s;
    } else if (idx < 8 * 4096 + 512) {
        const int j = idx - 8 * 4096;
        const int h = j >> 6, m = j & 63;
        float s = 0.f;
        for (int b = 0; b < S; ++b) s += pSum[((size_t)h * S + b) * 64 + m];
        Ksum[j] = s;
    }
}

// ---------- kernel 3: Qp -> Z -> out (zero barriers; unchanged from R5) ----------
__global__ __launch_bounds__(256, 2)
void out_kernel(const bf16* __restrict__ xb,
                const bf16* __restrict__ WqpT, const float* __restrict__ fqb,
                const bf16* __restrict__ KVT, const float* __restrict__ Ksum,
                const bf16* __restrict__ WoT, const float* __restrict__ bo,
                float* __restrict__ out)
{
    __shared__ __align__(16) bf16 tbufs[4][32 * LDPA];   // 4 x 4608 B
    const int t  = threadIdx.x;
    const int w  = t >> 6;
    const int l  = t & 63;
    const int lr = l & 15;
    const int lk = l >> 4;
    bf16* tbuf = tbufs[w];
    const int nbase = blockIdx.x * 128 + w * 32;

    const int r0 = min(nbase + lr,      NN - 1);
    const int r1 = min(nbase + 16 + lr, NN - 1);
    const bf16* xb0 = xb + (size_t)r0 * 256;
    const bf16* xb1 = xb + (size_t)r1 * 256;
    bf16x8 xa[2][8];
#pragma unroll
    for (int kk = 0; kk < 8; ++kk) {
        const int off = kk * 32 + lk * 8;
        xa[0][kk] = *reinterpret_cast<const bf16x8*>(xb0 + off);
        xa[1][kk] = *reinterpret_cast<const bf16x8*>(xb1 + off);
    }

    f32x4 oacc[2][4];
#pragma unroll
    for (int jt = 0; jt < 4; ++jt) {
        const float b = bo[jt * 16 + lr];
        oacc[0][jt] = (f32x4){b, b, b, b};
        oacc[1][jt] = oacc[0][jt];
    }

    for (int h = 0; h < 8; ++h) {
        // ---- Qfeat = x@Wqp + fqb ----
        f32x4 fQ[2][4];
#pragma unroll
        for (int mt = 0; mt < 4; ++mt) {
            const float b = fqb[h * 64 + mt * 16 + lr];
            fQ[0][mt] = (f32x4){b, b, b, b};
            fQ[1][mt] = fQ[0][mt];
        }
#pragma unroll
        for (int kk = 0; kk < 8; ++kk) {
#pragma unroll
            for (int mt = 0; mt < 4; ++mt) {
                const bf16x8 wb = *reinterpret_cast<const bf16x8*>(
                    &WqpT[(size_t)(h * 64 + mt * 16 + lr) * 256 + kk * 32 + lk * 8]);
                fQ[0][mt] = MFMA(xa[0][kk], wb, fQ[0][mt]);
                fQ[1][mt] = MFMA(xa[1][kk], wb, fQ[1][mt]);
            }
        }

        // ---- qp = exp(SCALE*feat)+eps; den partials; write qp -> tbuf ----
        lds_fence();   // drain previous head's za reads
        float denp[2][4] = {{0.f,0.f,0.f,0.f},{0.f,0.f,0.f,0.f}};
#pragma unroll
        for (int rt = 0; rt < 2; ++rt)
#pragma unroll
            for (int mt = 0; mt < 4; ++mt) {
                const float ks = Ksum[h * 64 + mt * 16 + lr];
#pragma unroll
                for (int r = 0; r < 4; ++r) {
                    const float qp = __expf(SCALE * fQ[rt][mt][r]) + EPSF;
                    denp[rt][r] += qp * ks;
                    tbuf[(rt * 16 + lk * 4 + r) * LDPA + mt * 16 + lr] = (bf16)qp;
                }
            }
#pragma unroll
        for (int rt = 0; rt < 2; ++rt)
#pragma unroll
            for (int r = 0; r < 4; ++r) {
                float s = denp[rt][r];
                s += __shfl_xor(s, 1, 64);
                s += __shfl_xor(s, 2, 64);
                s += __shfl_xor(s, 4, 64);
                s += __shfl_xor(s, 8, 64);
                denp[rt][r] = s;
            }
        lds_fence();

        // ---- num = Qp @ KV ----
        bf16x8 qpa[2][2];
#pragma unroll
        for (int rt = 0; rt < 2; ++rt)
#pragma unroll
            for (int kk = 0; kk < 2; ++kk)
                qpa[rt][kk] = *reinterpret_cast<const bf16x8*>(
                    &tbuf[(rt * 16 + lr) * LDPA + kk * 32 + lk * 8]);
        f32x4 num[2][4];
#pragma unroll
        for (int dt = 0; dt < 4; ++dt) { num[0][dt] = (f32x4){0.f,0.f,0.f,0.f}; num[1][dt] = num[0][dt]; }
#pragma unroll
        for (int dt = 0; dt < 4; ++dt)
#pragma unroll
            for (int kk = 0; kk < 2; ++kk) {
                const bf16x8 kvb = *reinterpret_cast<const bf16x8*>(
                    &KVT[h * 4096 + (dt * 16 + lr) * 64 + kk * 32 + lk * 8]);
                num[0][dt] = MFMA(qpa[0][kk], kvb, num[0][dt]);
                num[1][dt] = MFMA(qpa[1][kk], kvb, num[1][dt]);
            }

        // ---- z = num/den -> tbuf ----
        lds_fence();   // drain qpa reads
#pragma unroll
        for (int rt = 0; rt < 2; ++rt)
#pragma unroll
            for (int dt = 0; dt < 4; ++dt)
#pragma unroll
                for (int r = 0; r < 4; ++r)
                    tbuf[(rt * 16 + lk * 4 + r) * LDPA + dt * 16 + lr] =
                        (bf16)(num[rt][dt][r] / (denp[rt][r] + EPSF));
        lds_fence();

        // ---- out += Z @ Wo_h ----
        bf16x8 za[2][2];
#pragma unroll
        for (int rt = 0; rt < 2; ++rt)
#pragma unroll
            for (int kk = 0; kk < 2; ++kk)
                za[rt][kk] = *reinterpret_cast<const bf16x8*>(
                    &tbuf[(rt * 16 + lr) * LDPA + kk * 32 + lk * 8]);
#pragma unroll
        for (int jt = 0; jt < 4; ++jt)
#pragma unroll
            for (int kk = 0; kk < 2; ++kk) {
                const bf16x8 wo = *reinterpret_cast<const bf16x8*>(
                    &WoT[(size_t)(jt * 16 + lr) * HDIM + h * 64 + kk * 32 + lk * 8]);
                oacc[0][jt] = MFMA(za[0][kk], wo, oacc[0][jt]);
                oacc[1][jt] = MFMA(za[1][kk], wo, oacc[1][jt]);
            }
    }

#pragma unroll
    for (int rt = 0; rt < 2; ++rt)
#pragma unroll
        for (int jt = 0; jt < 4; ++jt)
#pragma unroll
            for (int r = 0; r < 4; ++r) {
                const int n = nbase + rt * 16 + lk * 4 + r;
                if (n < NN) out[(size_t)n * 64 + jt * 16 + lr] = oacc[rt][jt][r];
            }
}

extern "C" void kernel_launch(void* const* d_in, const int* in_sizes, int n_in,
                              void* d_out, int out_size, void* d_ws, size_t ws_size,
                              hipStream_t stream) {
    const float* x    = (const float*)d_in[0];
    const float* Wq   = (const float*)d_in[1];
    const float* bq   = (const float*)d_in[2];
    const float* Wk   = (const float*)d_in[3];
    const float* bk   = (const float*)d_in[4];
    const float* Wv   = (const float*)d_in[5];
    const float* bv   = (const float*)d_in[6];
    const float* Wo   = (const float*)d_in[7];
    const float* bo   = (const float*)d_in[8];
    const float* proj = (const float*)d_in[9];
    float* out = (float*)d_out;

    // workspace layout (bytes)
    char* ws = (char*)d_ws;
    float* Ksum = (float*)(ws + 0);           // 2048
    float* fqb  = (float*)(ws + 2048);        // 2048
    float* fkb  = (float*)(ws + 4096);        // 2048
    bf16*  WqpT = (bf16*)(ws + 6144);         // 262144
    bf16*  WkpT = (bf16*)(ws + 268288);       // 262144
    bf16*  WvT  = (bf16*)(ws + 530432);       // 262144
    bf16*  WoT  = (bf16*)(ws + 792576);       // 65536
    bf16*  KVT  = (bf16*)(ws + 858112);       // 65536
    bf16*  xb   = (bf16*)(ws + 923648);       // 25600000
    const size_t fixed = 26523648ull;
    // per-slice: pSum 8*64*4 = 2048 B, pKV 8*4096*2 = 65536 B -> 67584 B
    size_t avail = (ws_size > fixed) ? (ws_size - fixed) / 67584ull : 64;
    int S   = (int)(avail < 512 ? avail : 512);
    int bsh = 0;                               // G=8 heads/block
    if (S < 384) bsh = 1;                      // G=4: 2 blocks/slice to keep grid full
    if (S < 1) S = 1;
    float* pSum = (float*)(ws + fixed);                      // S*2048
    bf16*  pKV  = (bf16*) (ws + fixed + (size_t)S * 2048);   // S*65536

    prep_kernel<<<dim3(1156), 256, 0, stream>>>(Wq, bq, Wk, bk, Wv, Wo, proj,
                                                WqpT, WkpT, WvT, WoT, fqb, fkb);
    xconv_kernel<<<dim3(2048), 256, 0, stream>>>(x, xb);
    if (bsh == 0)
        kv_kernel<2, 0><<<dim3(S), 256, 0, stream>>>(xb, WkpT, fkb, WvT, bv,
                                                     pKV, pSum, S);
    else
        kv_kernel<1, 1><<<dim3(2 * S), 256, 0, stream>>>(xb, WkpT, fkb, WvT, bv,
                                                         pKV, pSum, S);
    reduce_kernel<<<dim3(130), 256, 0, stream>>>(pKV, pSum, KVT, Ksum, S);
    out_kernel<<<dim3(NCH128), 256, 0, stream>>>(xb, WqpT, fqb, KVT, Ksum,
                                                 WoT, bo, out);
}

// Round 7
// 370.959 us; speedup vs baseline: 1.9106x; 1.9106x over previous
//
#include <hip/hip_runtime.h>

// Performer attention (HyperGTConv): N=50000, C=256, H=8, D=M=64.
// Round 7: kill the spills (VGPR=128 cap + 128-reg accumulators since R4).
//  - amdgpu_waves_per_eu(2,2): pin 2 waves/EU -> 256-VGPR budget, no scratch.
//  - kv: 512-thread blocks, wave = 1 head, 8 waves = 8 heads share each 32-row
//    x chunk (x read once device-wide). K-GEMM and V-GEMM in separate passes
//    so fK/aV are never both live. Zero __syncthreads.
//  - out: 512-thread blocks (8 waves x 32 rows), grid 196 ~ 1/CU.
//  - prep + xconv merged (independent block ranges).

#define NN      50000
#define HDIM    512
#define EPSF    1e-6f
#define SCALE   0.044194173824159224f   // (1/sqrt(64)) * 64^(-1/4)
#define NCH32   1563                    // ceil(50000/32)  (kv chunk count)
#define NCH256  196                     // ceil(50000/256) (out blocks)
#define LDPA    72                      // out strip pitch (bf16)
#define LDPB    40                      // kv transposed strip pitch (bf16)

typedef __bf16 bf16;
typedef __bf16 bf16x4 __attribute__((ext_vector_type(4)));
typedef __bf16 bf16x8 __attribute__((ext_vector_type(8)));
typedef float  f32x4  __attribute__((ext_vector_type(4)));

#define MFMA(a, b, c) __builtin_amdgcn_mfma_f32_16x16x32_bf16((a), (b), (c), 0, 0, 0)

__device__ __forceinline__ void lds_fence() {
    asm volatile("s_waitcnt lgkmcnt(0)" ::: "memory");
}

// ---------- prepx: xconv (blocks 0..2047) + weight fold/transpose (2048..) ----------
__global__ void prepx_kernel(const float* __restrict__ x, bf16* __restrict__ xb,
                             const float* __restrict__ Wq, const float* __restrict__ bq,
                             const float* __restrict__ Wk, const float* __restrict__ bk,
                             const float* __restrict__ Wv, const float* __restrict__ Wo,
                             const float* __restrict__ proj,
                             bf16* __restrict__ WqpT, bf16* __restrict__ WkpT,
                             bf16* __restrict__ WvT, bf16* __restrict__ WoT,
                             float* __restrict__ fqb, float* __restrict__ fkb)
{
    if (blockIdx.x < 2048) {
        for (int i8 = blockIdx.x * 256 + threadIdx.x; i8 < NN * 256 / 8;
             i8 += 2048 * 256) {
            const float4 a = reinterpret_cast<const float4*>(x)[i8 * 2];
            const float4 b = reinterpret_cast<const float4*>(x)[i8 * 2 + 1];
            bf16x8 r;
            r[0] = (bf16)a.x; r[1] = (bf16)a.y; r[2] = (bf16)a.z; r[3] = (bf16)a.w;
            r[4] = (bf16)b.x; r[5] = (bf16)b.y; r[6] = (bf16)b.z; r[7] = (bf16)b.w;
            reinterpret_cast<bf16x8*>(xb)[i8] = r;
        }
        return;
    }
    const int t = (blockIdx.x - 2048) * 256 + threadIdx.x;
    if (t < 131072) {                       // WqpT/WkpT [h*64+m][c] = sum_d W[c][h,d] proj[m][d]
        const int row = t >> 8, c = t & 255;
        const int hh = row >> 6, m = row & 63;
        const float* pr = proj + m * 64;
        const float* wq = Wq + (size_t)c * HDIM + hh * 64;
        const float* wk = Wk + (size_t)c * HDIM + hh * 64;
        float sq = 0.f, sk = 0.f;
        for (int d = 0; d < 64; ++d) { const float p = pr[d]; sq += wq[d] * p; sk += wk[d] * p; }
        WqpT[(size_t)row * 256 + c] = (bf16)sq;
        WkpT[(size_t)row * 256 + c] = (bf16)sk;
    } else if (t < 262144) {                // WvT[col][c] = Wv[c][col]
        const int i = t - 131072;
        const int col = i >> 8, c = i & 255;
        WvT[i] = (bf16)Wv[(size_t)c * HDIM + col];
    } else if (t < 262144 + 32768) {        // WoT[j][dp] = Wo[dp][j]
        const int i = t - 262144;
        const int j = i >> 9, dp = i & 511;
        WoT[i] = (bf16)Wo[(size_t)dp * 64 + j];
    } else if (t < 262144 + 32768 + 1024) { // fqb/fkb[h*64+m] = sum_d b[h,d] proj[m][d]
        const int i = t - 262144 - 32768;
        const int which = i >> 9, row = i & 511;
        const int hh = row >> 6, m = row & 63;
        const float* pr = proj + m * 64;
        const float* b = (which ? bk : bq) + hh * 64;
        float s = 0.f;
        for (int d = 0; d < 64; ++d) s += b[d] * pr[d];
        (which ? fkb : fqb)[row] = s;
    }
}

// ---------- kernel 1: KV partials. 8 waves = 8 heads, shared 32-row chunks ----------
__global__ void __launch_bounds__(512)
__attribute__((amdgpu_waves_per_eu(2, 2)))
kv_kernel(const bf16* __restrict__ xb,
          const bf16* __restrict__ WkpT, const float* __restrict__ fkb,
          const bf16* __restrict__ WvT,  const float* __restrict__ bv,
          bf16* __restrict__ pKV, float* __restrict__ pSum, int S)
{
    __shared__ __align__(16) bf16 pool[8][2][64 * LDPB];   // 81920 B
    const int t  = threadIdx.x;
    const int h  = t >> 6;     // wave index == head
    const int l  = t & 63;
    const int lr = l & 15;
    const int lk = l >> 4;
    const int slice = blockIdx.x;

    bf16* kptbuf = pool[h][0];   // [64 m][LDPB n]
    bf16* vtbuf  = pool[h][1];   // [64 d][LDPB n]

    f32x4 kvacc[16];
#pragma unroll
    for (int i = 0; i < 16; ++i) kvacc[i] = (f32x4){0.f, 0.f, 0.f, 0.f};
    float ksum_acc[4] = {0.f, 0.f, 0.f, 0.f};

    float fkbc[4], bvc[4];
#pragma unroll
    for (int q = 0; q < 4; ++q) {
        fkbc[q] = fkb[h * 64 + q * 16 + lr];
        bvc [q] = bv [h * 64 + q * 16 + lr];
    }

    for (int chunk = slice; chunk < NCH32; chunk += S) {
        const int nbase = chunk * 32;
        const int r0 = min(nbase + lr,      NN - 1);
        const int r1 = min(nbase + 16 + lr, NN - 1);
        const bf16* xb0 = xb + (size_t)r0 * 256;
        const bf16* xb1 = xb + (size_t)r1 * 256;

        // ---- pass 1: Kfeat = x@Wkp + fkb (only fK live) ----
        f32x4 fK[2][4];
#pragma unroll
        for (int q = 0; q < 4; ++q) {
            fK[0][q] = (f32x4){fkbc[q], fkbc[q], fkbc[q], fkbc[q]};
            fK[1][q] = fK[0][q];
        }
#pragma unroll
        for (int kk = 0; kk < 8; ++kk) {
            const int off = kk * 32 + lk * 8;
            const bf16x8 xa0 = *reinterpret_cast<const bf16x8*>(xb0 + off);
            const bf16x8 xa1 = *reinterpret_cast<const bf16x8*>(xb1 + off);
#pragma unroll
            for (int mt = 0; mt < 4; ++mt) {
                const bf16x8 wb = *reinterpret_cast<const bf16x8*>(
                    &WkpT[(size_t)(h * 64 + mt * 16 + lr) * 256 + off]);
                fK[0][mt] = MFMA(xa0, wb, fK[0][mt]);
                fK[1][mt] = MFMA(xa1, wb, fK[1][mt]);
            }
        }

        lds_fence();   // previous chunk's kpa/vb ds_reads drained
        // ---- exp -> Kp^T [m][n] (fK dies here) ----
#pragma unroll
        for (int rt = 0; rt < 2; ++rt)
#pragma unroll
            for (int q = 0; q < 4; ++q) {
                bf16x4 kp4;
#pragma unroll
                for (int r = 0; r < 4; ++r) {
                    const int nl = rt * 16 + lk * 4 + r;
                    const float kpv = ((nbase + nl) < NN)
                                          ? (__expf(SCALE * fK[rt][q][r]) + EPSF) : 0.f;
                    ksum_acc[q] += kpv;
                    kp4[r] = (bf16)kpv;
                }
                *reinterpret_cast<bf16x4*>(
                    &kptbuf[(q * 16 + lr) * LDPB + rt * 16 + lk * 4]) = kp4;
            }

        // ---- pass 2: V = x@Wv + bv (only aV live) ----
        f32x4 aV[2][4];
#pragma unroll
        for (int q = 0; q < 4; ++q) {
            aV[0][q] = (f32x4){bvc[q], bvc[q], bvc[q], bvc[q]};
            aV[1][q] = aV[0][q];
        }
#pragma unroll
        for (int kk = 0; kk < 8; ++kk) {
            const int off = kk * 32 + lk * 8;
            const bf16x8 xa0 = *reinterpret_cast<const bf16x8*>(xb0 + off);
            const bf16x8 xa1 = *reinterpret_cast<const bf16x8*>(xb1 + off);
#pragma unroll
            for (int dt = 0; dt < 4; ++dt) {
                const bf16x8 wb = *reinterpret_cast<const bf16x8*>(
                    &WvT[(size_t)(h * 64 + dt * 16 + lr) * 256 + off]);
                aV[0][dt] = MFMA(xa0, wb, aV[0][dt]);
                aV[1][dt] = MFMA(xa1, wb, aV[1][dt]);
            }
        }
        // ---- V^T [d][n] ----
#pragma unroll
        for (int rt = 0; rt < 2; ++rt)
#pragma unroll
            for (int q = 0; q < 4; ++q) {
                bf16x4 vv4;
#pragma unroll
                for (int r = 0; r < 4; ++r) {
                    const int nl = rt * 16 + lk * 4 + r;
                    vv4[r] = ((nbase + nl) < NN) ? (bf16)aV[rt][q][r] : (bf16)0.f;
                }
                *reinterpret_cast<bf16x4*>(
                    &vtbuf[(q * 16 + lr) * LDPB + rt * 16 + lk * 4]) = vv4;
            }
        lds_fence();   // writes visible to whole wave

        // ---- KV += Kp^T @ V ----
        bf16x8 kpa[4], vb[4];
#pragma unroll
        for (int mt = 0; mt < 4; ++mt)
            kpa[mt] = *reinterpret_cast<const bf16x8*>(
                &kptbuf[(mt * 16 + lr) * LDPB + lk * 8]);
#pragma unroll
        for (int dt = 0; dt < 4; ++dt)
            vb[dt] = *reinterpret_cast<const bf16x8*>(
                &vtbuf[(dt * 16 + lr) * LDPB + lk * 8]);
#pragma unroll
        for (int mt = 0; mt < 4; ++mt)
#pragma unroll
            for (int dt = 0; dt < 4; ++dt)
                kvacc[mt * 4 + dt] = MFMA(kpa[mt], vb[dt], kvacc[mt * 4 + dt]);
    }

    // ---- epilogue (per-wave, no barriers): bf16 partial KV + fp32 ksum ----
    bf16* dst = pKV + ((size_t)h * S + slice) * 4096;
#pragma unroll
    for (int mt = 0; mt < 4; ++mt)
#pragma unroll
        for (int dt = 0; dt < 4; ++dt)
#pragma unroll
            for (int r = 0; r < 4; ++r)
                dst[(mt * 16 + lk * 4 + r) * 64 + dt * 16 + lr] =
                    (bf16)kvacc[mt * 4 + dt][r];
#pragma unroll
    for (int q = 0; q < 4; ++q) {
        float s = ksum_acc[q];
        s += __shfl_xor(s, 16, 64);
        s += __shfl_xor(s, 32, 64);
        if (lk == 0)
            pSum[((size_t)h * S + slice) * 64 + q * 16 + lr] = s;
    }
}

// ---------- reduce: bf16 partials -> KVT bf16 [h][d][m] + Ksum fp32 ----------
__global__ void reduce_kernel(const bf16* __restrict__ pKV, const float* __restrict__ pSum,
                              bf16* __restrict__ KVT, float* __restrict__ Ksum, int S)
{
    const int idx = blockIdx.x * 256 + threadIdx.x;
    if (idx < 8 * 4096) {
        const int h = idx >> 12, md = idx & 4095;
        const int m = md >> 6, d = md & 63;
        float s = 0.f;
        for (int b = 0; b < S; ++b) s += (float)pKV[((size_t)h * S + b) * 4096 + md];
        KVT[h * 4096 + d * 64 + m] = (bf16)s;
    } else if (idx < 8 * 4096 + 512) {
        const int j = idx - 8 * 4096;
        const int h = j >> 6, m = j & 63;
        float s = 0.f;
        for (int b = 0; b < S; ++b) s += pSum[((size_t)h * S + b) * 64 + m];
        Ksum[j] = s;
    }
}

// ---------- kernel 3: Qp -> Z -> out (8 waves x 32 rows, zero barriers) ----------
__global__ void __launch_bounds__(512)
__attribute__((amdgpu_waves_per_eu(2, 2)))
out_kernel(const bf16* __restrict__ xb,
           const bf16* __restrict__ WqpT, const float* __restrict__ fqb,
           const bf16* __restrict__ KVT, const float* __restrict__ Ksum,
           const bf16* __restrict__ WoT, const float* __restrict__ bo,
           float* __restrict__ out)
{
    __shared__ __align__(16) bf16 tbufs[8][32 * LDPA];   // 36864 B
    const int t  = threadIdx.x;
    const int w  = t >> 6;
    const int l  = t & 63;
    const int lr = l & 15;
    const int lk = l >> 4;
    bf16* tbuf = tbufs[w];
    const int nbase = blockIdx.x * 256 + w * 32;

    const int r0 = min(nbase + lr,      NN - 1);
    const int r1 = min(nbase + 16 + lr, NN - 1);
    const bf16* xb0 = xb + (size_t)r0 * 256;
    const bf16* xb1 = xb + (size_t)r1 * 256;
    bf16x8 xa[2][8];
#pragma unroll
    for (int kk = 0; kk < 8; ++kk) {
        const int off = kk * 32 + lk * 8;
        xa[0][kk] = *reinterpret_cast<const bf16x8*>(xb0 + off);
        xa[1][kk] = *reinterpret_cast<const bf16x8*>(xb1 + off);
    }

    f32x4 oacc[2][4];
#pragma unroll
    for (int jt = 0; jt < 4; ++jt) {
        const float b = bo[jt * 16 + lr];
        oacc[0][jt] = (f32x4){b, b, b, b};
        oacc[1][jt] = oacc[0][jt];
    }

    for (int h = 0; h < 8; ++h) {
        // ---- Qfeat = x@Wqp + fqb ----
        f32x4 fQ[2][4];
#pragma unroll
        for (int mt = 0; mt < 4; ++mt) {
            const float b = fqb[h * 64 + mt * 16 + lr];
            fQ[0][mt] = (f32x4){b, b, b, b};
            fQ[1][mt] = fQ[0][mt];
        }
#pragma unroll
        for (int kk = 0; kk < 8; ++kk) {
#pragma unroll
            for (int mt = 0; mt < 4; ++mt) {
                const bf16x8 wb = *reinterpret_cast<const bf16x8*>(
                    &WqpT[(size_t)(h * 64 + mt * 16 + lr) * 256 + kk * 32 + lk * 8]);
                fQ[0][mt] = MFMA(xa[0][kk], wb, fQ[0][mt]);
                fQ[1][mt] = MFMA(xa[1][kk], wb, fQ[1][mt]);
            }
        }

        // ---- qp = exp(SCALE*feat)+eps; den partials; qp -> tbuf ----
        lds_fence();   // drain previous head's za reads
        float denp[2][4] = {{0.f,0.f,0.f,0.f},{0.f,0.f,0.f,0.f}};
#pragma unroll
        for (int rt = 0; rt < 2; ++rt)
#pragma unroll
            for (int mt = 0; mt < 4; ++mt) {
                const float ks = Ksum[h * 64 + mt * 16 + lr];
#pragma unroll
                for (int r = 0; r < 4; ++r) {
                    const float qp = __expf(SCALE * fQ[rt][mt][r]) + EPSF;
                    denp[rt][r] += qp * ks;
                    tbuf[(rt * 16 + lk * 4 + r) * LDPA + mt * 16 + lr] = (bf16)qp;
                }
            }
#pragma unroll
        for (int rt = 0; rt < 2; ++rt)
#pragma unroll
            for (int r = 0; r < 4; ++r) {
                float s = denp[rt][r];
                s += __shfl_xor(s, 1, 64);
                s += __shfl_xor(s, 2, 64);
                s += __shfl_xor(s, 4, 64);
                s += __shfl_xor(s, 8, 64);
                denp[rt][r] = s;
            }
        lds_fence();

        // ---- num = Qp @ KV ----
        bf16x8 qpa[2][2];
#pragma unroll
        for (int rt = 0; rt < 2; ++rt)
#pragma unroll
            for (int kk = 0; kk < 2; ++kk)
                qpa[rt][kk] = *reinterpret_cast<const bf16x8*>(
                    &tbuf[(rt * 16 + lr) * LDPA + kk * 32 + lk * 8]);
        f32x4 num[2][4];
#pragma unroll
        for (int dt = 0; dt < 4; ++dt) { num[0][dt] = (f32x4){0.f,0.f,0.f,0.f}; num[1][dt] = num[0][dt]; }
#pragma unroll
        for (int dt = 0; dt < 4; ++dt)
#pragma unroll
            for (int kk = 0; kk < 2; ++kk) {
                const bf16x8 kvb = *reinterpret_cast<const bf16x8*>(
                    &KVT[h * 4096 + (dt * 16 + lr) * 64 + kk * 32 + lk * 8]);
                num[0][dt] = MFMA(qpa[0][kk], kvb, num[0][dt]);
                num[1][dt] = MFMA(qpa[1][kk], kvb, num[1][dt]);
            }

        // ---- z = num/den -> tbuf ----
        lds_fence();   // drain qpa reads
#pragma unroll
        for (int rt = 0; rt < 2; ++rt)
#pragma unroll
            for (int dt = 0; dt < 4; ++dt)
#pragma unroll
                for (int r = 0; r < 4; ++r)
                    tbuf[(rt * 16 + lk * 4 + r) * LDPA + dt * 16 + lr] =
                        (bf16)(num[rt][dt][r] / (denp[rt][r] + EPSF));
        lds_fence();

        // ---- out += Z @ Wo_h ----
        bf16x8 za[2][2];
#pragma unroll
        for (int rt = 0; rt < 2; ++rt)
#pragma unroll
            for (int kk = 0; kk < 2; ++kk)
                za[rt][kk] = *reinterpret_cast<const bf16x8*>(
                    &tbuf[(rt * 16 + lr) * LDPA + kk * 32 + lk * 8]);
#pragma unroll
        for (int jt = 0; jt < 4; ++jt)
#pragma unroll
            for (int kk = 0; kk < 2; ++kk) {
                const bf16x8 wo = *reinterpret_cast<const bf16x8*>(
                    &WoT[(size_t)(jt * 16 + lr) * HDIM + h * 64 + kk * 32 + lk * 8]);
                oacc[0][jt] = MFMA(za[0][kk], wo, oacc[0][jt]);
                oacc[1][jt] = MFMA(za[1][kk], wo, oacc[1][jt]);
            }
    }

#pragma unroll
    for (int rt = 0; rt < 2; ++rt)
#pragma unroll
        for (int jt = 0; jt < 4; ++jt)
#pragma unroll
            for (int r = 0; r < 4; ++r) {
                const int n = nbase + rt * 16 + lk * 4 + r;
                if (n < NN) out[(size_t)n * 64 + jt * 16 + lr] = oacc[rt][jt][r];
            }
}

extern "C" void kernel_launch(void* const* d_in, const int* in_sizes, int n_in,
                              void* d_out, int out_size, void* d_ws, size_t ws_size,
                              hipStream_t stream) {
    const float* x    = (const float*)d_in[0];
    const float* Wq   = (const float*)d_in[1];
    const float* bq   = (const float*)d_in[2];
    const float* Wk   = (const float*)d_in[3];
    const float* bk   = (const float*)d_in[4];
    const float* Wv   = (const float*)d_in[5];
    const float* bv   = (const float*)d_in[6];
    const float* Wo   = (const float*)d_in[7];
    const float* bo   = (const float*)d_in[8];
    const float* proj = (const float*)d_in[9];
    float* out = (float*)d_out;

    // workspace layout (bytes)
    char* ws = (char*)d_ws;
    float* Ksum = (float*)(ws + 0);           // 2048
    float* fqb  = (float*)(ws + 2048);        // 2048
    float* fkb  = (float*)(ws + 4096);        // 2048
    bf16*  WqpT = (bf16*)(ws + 6144);         // 262144
    bf16*  WkpT = (bf16*)(ws + 268288);       // 262144
    bf16*  WvT  = (bf16*)(ws + 530432);       // 262144
    bf16*  WoT  = (bf16*)(ws + 792576);       // 65536
    bf16*  KVT  = (bf16*)(ws + 858112);       // 65536
    bf16*  xb   = (bf16*)(ws + 923648);       // 25600000
    const size_t fixed = 26523648ull;
    // per-slice: pSum 8*64*4 = 2048 B, pKV 8*4096*2 = 65536 B -> 67584 B
    size_t avail = (ws_size > fixed) ? (ws_size - fixed) / 67584ull : 1;
    int S = (int)(avail < 256 ? avail : 256);
    if (S < 1) S = 1;
    float* pSum = (float*)(ws + fixed);                      // S*2048
    bf16*  pKV  = (bf16*) (ws + fixed + (size_t)S * 2048);   // S*65536

    prepx_kernel<<<dim3(2048 + 1156), 256, 0, stream>>>(
        x, xb, Wq, bq, Wk, bk, Wv, Wo, proj, WqpT, WkpT, WvT, WoT, fqb, fkb);
    kv_kernel<<<dim3(S), 512, 0, stream>>>(xb, WkpT, fkb, WvT, bv, pKV, pSum, S);
    reduce_kernel<<<dim3(130), 256, 0, stream>>>(pKV, pSum, KVT, Ksum, S);
    out_kernel<<<dim3(NCH256), 512, 0, stream>>>(xb, WqpT, fqb, KVT, Ksum,
                                                 WoT, bo, out);
}